// Round 1
// baseline (63530.658 us; speedup 1.0000x reference)
//
#include <hip/hip_runtime.h>
#include <hip/hip_cooperative_groups.h>

namespace cg = cooperative_groups;

#define NBLK 256
#define NTHR 512

constexpr int B_ = 128, H_ = 1024, HH_ = 256, NZ_ = 64, M_ = 20, NMAX_ = 128, LAT_ = 128;

// workspace layout (float offsets)
constexpr int WS_H    = 0;
constexpr int WS_C    = WS_H    + B_*H_;
constexpr int WS_HH0  = WS_C    + B_*H_;
constexpr int WS_HH1  = WS_HH0  + B_*HH_;
constexpr int WS_CH0  = WS_HH1  + B_*HH_;
constexpr int WS_CH1  = WS_CH0  + B_*HH_;
constexpr int WS_PREV = WS_CH1  + B_*HH_;     // 128*8
constexpr int WS_G    = WS_PREV + B_*8;       // 128*1024
constexpr int WS_GH   = WS_G    + B_*H_;      // 128*4096
constexpr int WS_CG4  = WS_GH   + B_*4096;    // 128*1024
constexpr int WS_CGX  = WS_CG4  + B_*H_;      // 128*4096
constexpr int WS_HWXH = WS_CGX  + B_*4096;    // 1024*1024 repacked hWx h-columns
constexpr int WS_WXP  = WS_HWXH + H_*H_;      // 5*4096  (Wx prev cols, transposed)
constexpr int WS_HWXP = WS_WXP  + 5*4096;     // 5*1024  (hWx prev cols, transposed)
constexpr int WS_ZG   = WS_HWXP + 5*H_;       // 128*768

struct SmemA { float h[16][516]; float hh[16][260]; float red[512]; float y[128]; };
struct SmemB { float hh[8][260]; };
struct SmemC { float zg[8][768]; float prev[8][8]; };
union  Smem  { SmemA a; SmemB b; SmemC c; };

__device__ __forceinline__ float dot4(const float4 a, const float4 b){
  return a.x*b.x + a.y*b.y + a.z*b.z + a.w*b.w;
}
__device__ __forceinline__ float sigf(float x){ return 1.0f/(1.0f + expf(-x)); }
__device__ __forceinline__ float gumb(float u){
  u = fminf(fmaxf(u, 1e-7f), 1.0f - 1e-7f);
  return -logf(-logf(u));
}

// projection + gumbel-argmax sampling for step t of batch b (one block)
__device__ void sample_step(int t, int b, Smem& sm, const float* hws,
    const float* projW, const float* projb, const float* eps_,
    const float* umix, const float* upen, float* out, float* prevws)
{
  const int tid = threadIdx.x;
  if (tid < 492){
    const int j = tid >> 2, q = tid & 3;
    const float4* h4 = (const float4*)(hws + b*H_ + q*256);
    const float4* w4 = (const float4*)(projW + j*H_ + q*256);
    float acc = 0.f;
    #pragma unroll 8
    for (int i=0;i<64;i++) acc += dot4(h4[i], w4[i]);
    sm.a.red[tid] = acc;
  }
  __syncthreads();
  if (tid < 123)
    sm.a.y[tid] = ((sm.a.red[tid*4+0] + sm.a.red[tid*4+1]) + sm.a.red[tid*4+2])
                  + sm.a.red[tid*4+3] + projb[tid];
  __syncthreads();
  if (tid == 0){
    const float* y = sm.a.y;
    int k = 0; float best = -INFINITY;
    for (int m=0;m<M_;m++){
      float v = y[m] + gumb(umix[(t*B_+b)*M_ + m]);
      if (v > best){ best = v; k = m; }          // first-max tie-break like argmax
    }
    const float mx = y[20+k], my = y[40+k];
    const float sx = expf(y[60+k]), sy = expf(y[80+k]);
    const float rho = tanhf(y[100+k]);
    const float e0 = eps_[(t*B_+b)*2+0], e1 = eps_[(t*B_+b)*2+1];
    const float dxs = mx + sx*e0;
    const float dys = my + sy*(rho*e0 + sqrtf(1.0f - rho*rho)*e1);
    int pidx = 0; best = -INFINITY;
    for (int p=0;p<3;p++){
      float v = y[120+p] + gumb(upen[(t*B_+b)*3 + p]);
      if (v > best){ best = v; pidx = p; }
    }
    float s0,s1,s2,s3,s4;
    if (pidx == 2){ s0=0.f; s1=0.f; s2=0.f; s3=0.f; s4=1.f; }
    else { s0=dxs; s1=dys; s2=(pidx==0)?1.f:0.f; s3=(pidx==1)?1.f:0.f; s4=0.f; }
    float* o5 = out + (t*B_+b)*5;
    o5[0]=s0; o5[1]=s1; o5[2]=s2; o5[3]=s3; o5[4]=s4;
    float* pr = prevws + b*8;
    pr[0]=s0; pr[1]=s1; pr[2]=s2; pr[3]=s3; pr[4]=s4;
  }
  __syncthreads();
}

extern "C" __global__ void __launch_bounds__(NTHR)
vae_kernel(const float* __restrict__ z,     const float* __restrict__ cls,
           const float* __restrict__ fcW,   const float* __restrict__ fcb,
           const float* __restrict__ Wx,    const float* __restrict__ Wh,
           const float* __restrict__ bias0, const float* __restrict__ hWx,
           const float* __restrict__ hWh,   const float* __restrict__ hb,
           const float* __restrict__ Whz_x, const float* __restrict__ Whz_h,
           const float* __restrict__ Whz_b, const float* __restrict__ Wdz_x,
           const float* __restrict__ Wdz_h, const float* __restrict__ Wdz_b,
           const float* __restrict__ projW, const float* __restrict__ projb,
           const float* __restrict__ eps_,  const float* __restrict__ umix,
           const float* __restrict__ upen,
           float* __restrict__ out, float* __restrict__ ws)
{
  cg::grid_group grid = cg::this_grid();
  __shared__ Smem sm;
  const int tid = threadIdx.x;
  const int bid = blockIdx.x;

  float* hws   = ws + WS_H;
  float* cws   = ws + WS_C;
  float* hh0   = ws + WS_HH0;
  float* hh1   = ws + WS_HH1;
  float* ch0   = ws + WS_CH0;
  float* ch1   = ws + WS_CH1;
  float* prevw = ws + WS_PREV;
  float* gws   = ws + WS_G;
  float* ghws  = ws + WS_GH;
  float* cg4   = ws + WS_CG4;
  float* cgx   = ws + WS_CGX;
  float* hwxh  = ws + WS_HWXH;
  float* wxp   = ws + WS_WXP;
  float* hwxp  = ws + WS_HWXP;
  float* zgws  = ws + WS_ZG;

  //==================== INIT (once per launch) ====================
  {
    const int T = bid*NTHR + tid;
    // (a) s = tanh(z @ fc_in_W.T + b) -> h0,c0,hh0,ch0   (tasks: 2560 o x 4 b-quads)
    if (T < 2560*4){
      const int o = T >> 2, bq = T & 3;
      const float4* wr = (const float4*)(fcW + o*LAT_);
      for (int bi=0;bi<32;bi++){
        const int b = bq*32 + bi;
        const float4* zr = (const float4*)(z + b*LAT_);
        float acc = fcb[o];
        #pragma unroll 8
        for (int i=0;i<LAT_/4;i++) acc += dot4(zr[i], wr[i]);
        const float v = tanhf(acc);
        if      (o < H_)        hws[b*H_ + o] = v;
        else if (o < 2*H_)      cws[b*H_ + (o - H_)] = v;
        else if (o < 2*H_+HH_)  hh0[b*HH_ + (o - 2*H_)] = v;
        else                    ch0[b*HH_ + (o - 2*H_ - HH_)] = v;
      }
    }
    // (b) Cg4 = [cls,z] @ hWx[:,5:143].T + hb   (tasks: 1024 j x 4 b-quads)
    if (T < 1024*4){
      const int j = T >> 2, bq = T & 3;
      const float* hr = hWx + j*1167;
      for (int bi=0;bi<32;bi++){
        const int b = bq*32 + bi;
        float acc = hb[j];
        for (int n=0;n<10;n++) acc += cls[b*10+n]*hr[5+n];
        const float* zr = z + b*LAT_;
        #pragma unroll 8
        for (int i=0;i<LAT_;i++) acc += zr[i]*hr[15+i];
        cg4[b*H_ + j] = acc;
      }
    }
    // (c) CgX = [cls,z] @ Wx[:,5:].T   (tasks: 4096 o x 4 b-quads)
    if (T < 4096*4){
      const int o = T >> 2, bq = T & 3;
      const float* wr = Wx + o*143;
      for (int bi=0;bi<32;bi++){
        const int b = bq*32 + bi;
        float acc = 0.f;
        for (int n=0;n<10;n++) acc += cls[b*10+n]*wr[5+n];
        const float* zr = z + b*LAT_;
        #pragma unroll 8
        for (int i=0;i<LAT_;i++) acc += zr[i]*wr[15+i];
        cgx[b*4096 + o] = acc;
      }
    }
    // (d) repack hWx h-columns to aligned [j][i]
    for (int idx = T; idx < H_*H_; idx += NBLK*NTHR)
      hwxh[idx] = hWx[(idx >> 10)*1167 + 143 + (idx & 1023)];
    // (e) prev-column transposes
    if (T < 5*4096) wxp[T]  = Wx[(T & 4095)*143 + (T >> 12)];
    if (T < 5*H_)   hwxp[T] = hWx[(T & 1023)*1167 + (T >> 10)];
    // (f) prev0 = [0,0,1,0,0]
    if (T < B_){
      float* pr = prevw + T*8;
      pr[0]=0.f; pr[1]=0.f; pr[2]=1.f; pr[3]=0.f; pr[4]=0.f; pr[5]=0.f; pr[6]=0.f; pr[7]=0.f;
    }
  }
  grid.sync();

  //==================== time loop ====================
  for (int t = 0; t < NMAX_; ++t){
    const float* hh_rd = (t & 1) ? hh1 : hh0;
    float*       hh_wr = (t & 1) ? hh0 : hh1;
    const float* ch_rd = (t & 1) ? ch1 : ch0;
    float*       ch_wr = (t & 1) ? ch0 : ch1;

    //---------------- PHASE A: GH = h@Wh.T ; G = h@hWxh.T + hh@hWh.T + Cg4 ----------------
    if (t > 0 && bid < B_)
      sample_step(t-1, bid, sm, hws, projW, projb, eps_, umix, upen, out, prevw);
    {
      const int bg = bid >> 5, s = bid & 31;
      const int brow = bg*16;
      const int tb = tid & 15, ts = tid >> 4;   // ts in [0,32)
      float accGH[4] = {0.f,0.f,0.f,0.f};
      float accG = 0.f;
      // stage hh tile (16 x 256)
      {
        const int lb = tid >> 5, lt = tid & 31;
        const float4* src = (const float4*)(hh_rd + (brow+lb)*HH_);
        float4* dst = (float4*)(&sm.a.hh[lb][0]);
        dst[lt] = src[lt]; dst[lt+32] = src[lt+32];
      }
      for (int chunk = 0; chunk < 2; ++chunk){
        {
          const int lb = tid >> 5, lt = tid & 31;
          const float4* src = (const float4*)(hws + (brow+lb)*H_ + chunk*512);
          float4* dst = (float4*)(&sm.a.h[lb][0]);
          dst[lt] = src[lt]; dst[lt+32] = src[lt+32]; dst[lt+64] = src[lt+64]; dst[lt+96] = src[lt+96];
        }
        __syncthreads();
        const float4* h4 = (const float4*)(&sm.a.h[tb][0]);
        const float4* w0 = (const float4*)(Wh + (s*128 +  0 + ts)*H_ + chunk*512);
        const float4* w1 = (const float4*)(Wh + (s*128 + 32 + ts)*H_ + chunk*512);
        const float4* w2 = (const float4*)(Wh + (s*128 + 64 + ts)*H_ + chunk*512);
        const float4* w3 = (const float4*)(Wh + (s*128 + 96 + ts)*H_ + chunk*512);
        const float4* wg = (const float4*)(hwxh + (s*32 + ts)*H_ + chunk*512);
        #pragma unroll 8
        for (int i=0;i<128;i++){
          const float4 hv = h4[i];
          accGH[0] += dot4(hv, w0[i]);
          accGH[1] += dot4(hv, w1[i]);
          accGH[2] += dot4(hv, w2[i]);
          accGH[3] += dot4(hv, w3[i]);
          accG     += dot4(hv, wg[i]);
        }
        __syncthreads();
      }
      {
        const float4* hh4 = (const float4*)(&sm.a.hh[tb][0]);
        const float4* wv  = (const float4*)(hWh + (s*32 + ts)*HH_);
        #pragma unroll 8
        for (int q=0;q<HH_/4;q++) accG += dot4(hh4[q], wv[q]);
        accG += cg4[(brow+tb)*H_ + s*32 + ts];
        gws[(brow+tb)*H_ + s*32 + ts] = accG;
      }
      float* ghp = ghws + (brow+tb)*4096;
      ghp[s*128 +  0 + ts] = accGH[0];
      ghp[s*128 + 32 + ts] = accGH[1];
      ghp[s*128 + 64 + ts] = accGH[2];
      ghp[s*128 + 96 + ts] = accGH[3];
    }
    grid.sync();

    //---------------- PHASE B: hyper-LSTM (redundant per block) + zg GEMM ----------------
    {
      const int bq = bid >> 4;       // 16 groups of 8 batches
      const int os = bid & 15;       // 16 zg-output slices of 48
      // hyper elementwise for this block's 8 batches (redundant across os; only os==0 writes state)
      for (int r = 0; r < 4; ++r){
        const int task = tid + r*NTHR;            // 2048 = 8b x 256jh
        const int lb = task >> 8, jh = task & 255;
        const int b = bq*8 + lb;
        float pv0=prevw[b*8+0], pv1=prevw[b*8+1], pv2=prevw[b*8+2], pv3=prevw[b*8+3], pv4=prevw[b*8+4];
        float g[4];
        #pragma unroll
        for (int gi=0; gi<4; ++gi){
          const int j = gi*HH_ + jh;
          float v = gws[b*H_ + j];
          v += pv0*hwxp[0*H_+j] + pv1*hwxp[1*H_+j] + pv2*hwxp[2*H_+j] + pv3*hwxp[3*H_+j] + pv4*hwxp[4*H_+j];
          g[gi] = v;
        }
        const float chn = sigf(g[1])*ch_rd[b*HH_+jh] + sigf(g[0])*tanhf(g[2]);
        const float hhn = sigf(g[3])*tanhf(chn);
        sm.b.hh[lb][jh] = hhn;
        if (os == 0){ ch_wr[b*HH_+jh] = chn; hh_wr[b*HH_+jh] = hhn; }
      }
      __syncthreads();
      // zg: 8 b x 48 outputs, dot-256 against Whz rows
      if (tid < 384){
        const int lb = tid / 48, ol = tid - lb*48;
        const int og = os*48 + ol;                 // [0,768)
        const int m = og >> 8, r = og & 255;
        const float* Wz = (m==0 ? Whz_x : (m==1 ? Whz_h : Whz_b)) + r*HH_;
        const float4* w4 = (const float4*)Wz;
        const float4* h4 = (const float4*)(&sm.b.hh[lb][0]);
        float acc = 0.f;
        #pragma unroll 8
        for (int q=0;q<HH_/4;q++) acc += dot4(h4[q], w4[q]);
        zgws[(bq*8+lb)*768 + og] = acc;
      }
    }
    grid.sync();

    //---------------- PHASE C: einsum + main LSTM ----------------
    {
      const int bg = bid >> 4;       // 16 groups of 8 batches
      const int js = bid & 15;       // 16 slices of 64 jh
      for (int r2 = tid; r2 < 8*768; r2 += NTHR){
        const int lb2 = r2 / 768, o2 = r2 - lb2*768;
        sm.c.zg[lb2][o2] = zgws[(bg*8+lb2)*768 + o2];
      }
      if (tid < 64){
        const int lb2 = tid >> 3, p = tid & 7;
        sm.c.prev[lb2][p] = (p < 5) ? prevw[(bg*8+lb2)*8 + p] : 0.f;
      }
      __syncthreads();
      const int lb = tid >> 6, jl = tid & 63;
      const int b = bg*8 + lb, jh = js*64 + jl;
      const float pv0=sm.c.prev[lb][0], pv1=sm.c.prev[lb][1], pv2=sm.c.prev[lb][2],
                  pv3=sm.c.prev[lb][3], pv4=sm.c.prev[lb][4];
      float pre[4];
      #pragma unroll
      for (int k=0;k<4;k++){
        const int row = k*H_ + jh;
        const float4* wx4 = (const float4*)(Wdz_x + row*NZ_);
        const float4* wh4 = (const float4*)(Wdz_h + row*NZ_);
        const float4* wb4 = (const float4*)(Wdz_b + row*NZ_);
        const float4* zx4 = (const float4*)(&sm.c.zg[lb][k*NZ_]);
        const float4* zh4 = (const float4*)(&sm.c.zg[lb][256 + k*NZ_]);
        const float4* zb4 = (const float4*)(&sm.c.zg[lb][512 + k*NZ_]);
        float dX=0.f, dH=0.f, dB=0.f;
        #pragma unroll
        for (int z4=0; z4<16; ++z4){
          dX += dot4(zx4[z4], wx4[z4]);
          dH += dot4(zh4[z4], wh4[z4]);
          dB += dot4(zb4[z4], wb4[z4]);
        }
        float gx = cgx[b*4096 + row];
        gx += pv0*wxp[0*4096+row] + pv1*wxp[1*4096+row] + pv2*wxp[2*4096+row]
            + pv3*wxp[3*4096+row] + pv4*wxp[4*4096+row];
        const float ghv = ghws[b*4096 + row];
        pre[k] = dX*gx + dH*ghv + dB + bias0[row];
      }
      const float cold = cws[b*H_ + jh];
      const float cn = sigf(pre[1])*cold + sigf(pre[0])*tanhf(pre[2]);
      const float hn = sigf(pre[3])*tanhf(cn);
      cws[b*H_ + jh] = cn;
      hws[b*H_ + jh] = hn;
    }
    grid.sync();
  }

  // final sampling for t = NMAX-1
  if (bid < B_)
    sample_step(NMAX_-1, bid, sm, hws, projW, projb, eps_, umix, upen, out, prevw);
}

extern "C" void kernel_launch(void* const* d_in, const int* in_sizes, int n_in,
                              void* d_out, int out_size, void* d_ws, size_t ws_size,
                              hipStream_t stream)
{
  const float* z     = (const float*)d_in[0];
  const float* cls   = (const float*)d_in[1];
  const float* fcW   = (const float*)d_in[2];
  const float* fcb   = (const float*)d_in[3];
  const float* Wx    = (const float*)d_in[4];
  const float* Wh    = (const float*)d_in[5];
  const float* bias0 = (const float*)d_in[6];
  const float* hWx   = (const float*)d_in[7];
  const float* hWh   = (const float*)d_in[8];
  const float* hb    = (const float*)d_in[9];
  const float* Whz_x = (const float*)d_in[10];
  const float* Whz_h = (const float*)d_in[11];
  const float* Whz_b = (const float*)d_in[12];
  const float* Wdz_x = (const float*)d_in[13];
  const float* Wdz_h = (const float*)d_in[14];
  const float* Wdz_b = (const float*)d_in[15];
  const float* projW = (const float*)d_in[16];
  const float* projb = (const float*)d_in[17];
  const float* eps_  = (const float*)d_in[18];
  const float* umix  = (const float*)d_in[19];
  const float* upen  = (const float*)d_in[20];
  float* out = (float*)d_out;
  float* ws  = (float*)d_ws;

  void* args[] = { (void*)&z, (void*)&cls, (void*)&fcW, (void*)&fcb, (void*)&Wx, (void*)&Wh,
                   (void*)&bias0, (void*)&hWx, (void*)&hWh, (void*)&hb,
                   (void*)&Whz_x, (void*)&Whz_h, (void*)&Whz_b,
                   (void*)&Wdz_x, (void*)&Wdz_h, (void*)&Wdz_b,
                   (void*)&projW, (void*)&projb, (void*)&eps_, (void*)&umix, (void*)&upen,
                   (void*)&out, (void*)&ws };
  hipLaunchCooperativeKernel((const void*)vae_kernel, dim3(NBLK), dim3(NTHR), args, 0, stream);
}

// Round 3
// 23115.663 us; speedup vs baseline: 2.7484x; 2.7484x over previous
//
#include <hip/hip_runtime.h>
#include <hip/hip_cooperative_groups.h>

namespace cg = cooperative_groups;

#define NBLK 256
#define NTHR 512

// workspace layout (float offsets)
constexpr int WS_H    = 0;            // 128*1024
constexpr int WS_HHS  = 131072;       // 128*256
constexpr int WS_Y    = 163840;       // 128*128
constexpr int WS_WEFF = 180224;       // 256*12288  (per-block folded hyper weights)

__device__ __forceinline__ float dot4(float4 a, float4 b){
  return a.x*b.x + a.y*b.y + a.z*b.z + a.w*b.w;
}
__device__ __forceinline__ float sigf(float x){ return 1.0f/(1.0f + expf(-x)); }
__device__ __forceinline__ float gumb(float u){
  u = fminf(fmaxf(u, 1e-7f), 1.0f - 1e-7f);
  return -logf(-logf(u));
}

extern "C" __global__ void __launch_bounds__(NTHR, 2)
vae_kernel(const float* __restrict__ z,     const float* __restrict__ cls,
           const float* __restrict__ fcW,   const float* __restrict__ fcb,
           const float* __restrict__ Wx,    const float* __restrict__ Wh,
           const float* __restrict__ bias0, const float* __restrict__ hWx,
           const float* __restrict__ hWh,   const float* __restrict__ hb,
           const float* __restrict__ Whz_x, const float* __restrict__ Whz_h,
           const float* __restrict__ Whz_b, const float* __restrict__ Wdz_x,
           const float* __restrict__ Wdz_h, const float* __restrict__ Wdz_b,
           const float* __restrict__ projW, const float* __restrict__ projb,
           const float* __restrict__ eps_,  const float* __restrict__ umix,
           const float* __restrict__ upen,
           float* __restrict__ out, float* __restrict__ ws)
{
  cg::grid_group grid = cg::this_grid();
  const int tid = threadIdx.x;
  const int bid = blockIdx.x;
  const int l = tid & 63;          // lane
  const int w = tid >> 6;          // wave 0..7
  const int rh = w & 1;            // row-half (P1)
  const int bq = w >> 1;           // b-quarter

  float* hws   = ws + WS_H;
  float* hhws  = ws + WS_HHS;
  float* yws   = ws + WS_Y;
  float* weffw = ws + WS_WEFF;

  __shared__ __align__(16) float lds_h[8192];    // 32KB h-tile; aliased as scr48 (6144) in P3
  __shared__ __align__(16) float lds_hh[2048];   // 8KB hh-tile
  __shared__ __align__(16) float lds_GH[2048];   // GH[b][16]
  __shared__ __align__(16) float lds_Gp[512];    // Gp[b][4]
  __shared__ __align__(16) float lds_prev[1024]; // prev[b][8]
  __shared__ float lds_wxp[80];                  // wxp[row16][5]
  __shared__ float lds_hwxp[20];                 // hwxp[gi][5]
  __shared__ float lds_b0[16];

  //==================== INIT ====================
  // --- persistent register weights ---
  float4 wWh[8][4];      // Wh rows (2rh+kk)*1024 + bid*4 + j, cols l*16..+16
  #pragma unroll
  for (int kk = 0; kk < 2; ++kk)
    #pragma unroll
    for (int j = 0; j < 4; ++j){
      const float4* src = (const float4*)(Wh + (((2*rh+kk)*1024 + bid*4 + j) << 10) + l*16);
      #pragma unroll
      for (int m = 0; m < 4; ++m) wWh[kk*4+j][m] = src[m];
    }
  float4 wHx[2][4];      // hWx rows (2rh+gi2)*256+bid, h-cols 143+l*16..
  #pragma unroll
  for (int gi2 = 0; gi2 < 2; ++gi2){
    const float* s = hWx + (size_t)((2*rh+gi2)*256 + bid)*1167 + 143 + l*16;
    #pragma unroll
    for (int m = 0; m < 4; ++m)
      wHx[gi2][m] = make_float4(s[m*4+0], s[m*4+1], s[m*4+2], s[m*4+3]);
  }
  float4 wHh[2];
  #pragma unroll
  for (int gi2 = 0; gi2 < 2; ++gi2)
    wHh[gi2] = *(const float4*)(hWh + (((2*rh+gi2)*256 + bid) << 8) + l*4);

  const bool isproj = (bid >= 128 && bid < 251);
  const int prow = bid - 128;
  float4 wPj[4] = {make_float4(0,0,0,0),make_float4(0,0,0,0),make_float4(0,0,0,0),make_float4(0,0,0,0)};
  float pjb = 0.f;
  if (isproj){
    const float4* src = (const float4*)(projW + (prow << 10) + l*16);
    #pragma unroll
    for (int m = 0; m < 4; ++m) wPj[m] = src[m];
    pjb = projb[prow];
  }

  // --- per-thread elementwise state (b = tid>>2, j = tid&3) ---
  const int eb = tid >> 2, ej = tid & 3;
  float cgxr[4];
  #pragma unroll
  for (int k = 0; k < 4; ++k){
    const float* wr = Wx + (size_t)(k*1024 + bid*4 + ej)*143;
    float a = 0.f;
    for (int n = 0; n < 10; ++n) a += cls[eb*10+n]*wr[5+n];
    const float* zr = z + (eb << 7);
    #pragma unroll 8
    for (int i = 0; i < 128; ++i) a += zr[i]*wr[15+i];
    cgxr[k] = a;
  }
  float cst;
  {
    int col = 1024 + bid*4 + ej;
    float a = fcb[col];
    const float* wr = fcW + (col << 7);
    const float* zr = z + (eb << 7);
    #pragma unroll 8
    for (int i = 0; i < 128; ++i) a += zr[i]*wr[i];
    cst = tanhf(a);
  }
  {
    int col = bid*4 + ej;
    float a = fcb[col];
    const float* wr = fcW + (col << 7);
    const float* zr = z + (eb << 7);
    #pragma unroll 8
    for (int i = 0; i < 128; ++i) a += zr[i]*wr[i];
    hws[(eb << 10) + col] = tanhf(a);
  }
  float cg4r[4] = {0,0,0,0};
  float chst = 0.f;
  if (tid < 128){
    int b = tid;
    const float* zr = z + (b << 7);
    #pragma unroll
    for (int gi = 0; gi < 4; ++gi){
      int row = gi*256 + bid;
      const float* wr = hWx + (size_t)row*1167;
      float a = hb[row];
      for (int n = 0; n < 10; ++n) a += cls[b*10+n]*wr[5+n];
      #pragma unroll 8
      for (int i = 0; i < 128; ++i) a += zr[i]*wr[15+i];
      cg4r[gi] = a;
    }
    {
      int col = 2304 + bid;
      float a = fcb[col];
      const float* wr = fcW + (col << 7);
      #pragma unroll 8
      for (int i = 0; i < 128; ++i) a += zr[i]*wr[i];
      chst = tanhf(a);
    }
    {
      int col = 2048 + bid;
      float a = fcb[col];
      const float* wr = fcW + (col << 7);
      #pragma unroll 8
      for (int i = 0; i < 128; ++i) a += zr[i]*wr[i];
      hhws[(b << 8) + bid] = tanhf(a);
    }
    lds_prev[tid*8+0] = 0.f; lds_prev[tid*8+1] = 0.f; lds_prev[tid*8+2] = 1.f;
    lds_prev[tid*8+3] = 0.f; lds_prev[tid*8+4] = 0.f;
  }
  if (tid < 80){
    int r16 = tid/5, p = tid - r16*5;
    lds_wxp[tid] = Wx[(size_t)((r16>>2)*1024 + bid*4 + (r16&3))*143 + p];
  }
  if (tid < 20){
    int gi = tid/5, p = tid - gi*5;
    lds_hwxp[tid] = hWx[(size_t)(gi*256 + bid)*1167 + p];
  }
  if (tid < 16) lds_b0[tid] = bias0[(tid>>2)*1024 + bid*4 + (tid&3)];

  // --- Weff fold: Weff_m[r16][c] = sum_z Wdz_m[row][z] * Whz_m[k*64+z][c] ---
  {
    const float* Wdzp[3] = {Wdz_x, Wdz_h, Wdz_b};
    const float* Whzp[3] = {Whz_x, Whz_h, Whz_b};
    for (int n = 0; n < 24; ++n){
      int gidx = tid + 512*n;            // = m*4096 + r*256 + c
      int m = gidx >> 12, rem = gidx & 4095;
      int r = rem >> 8, c = rem & 255;
      int k = r >> 2, j = r & 3;
      const float* wd = Wdzp[m] + (size_t)(k*1024 + bid*4 + j)*64;
      const float* wzb = Whzp[m] + c;
      float a = 0.f;
      #pragma unroll 8
      for (int zz = 0; zz < 64; ++zz) a += wd[zz]*wzb[(k*64+zz) << 8];
      weffw[(size_t)bid*12288 + gidx] = a;
    }
  }
  grid.sync();

  //==================== time loop ====================
  for (int t = 0; t <= 128; ++t){
    const bool full = (t < 128);
    //---------------- P1 ----------------
    if (full){
      for (int tile = 0; tile < 16; ++tile){
        __syncthreads();
        {
          const float4* hsrc = (const float4*)(hws + tile*8192);
          float4* hdst = (float4*)lds_h;
          #pragma unroll
          for (int n = 0; n < 4; ++n) hdst[tid + 512*n] = hsrc[tid + 512*n];
          ((float4*)lds_hh)[tid] = ((const float4*)(hhws + tile*2048))[tid];
        }
        __syncthreads();
        #pragma unroll
        for (int u = 0; u < 2; ++u){
          const int bloc = bq*2 + u;
          const int b = tile*8 + bloc;
          const float4* h4 = (const float4*)(lds_h + (bloc << 10)) + l*4;
          const float4 a0 = h4[0], a1 = h4[1], a2 = h4[2], a3 = h4[3];
          float acc[8];
          #pragma unroll
          for (int r8 = 0; r8 < 8; ++r8)
            acc[r8] = dot4(a0,wWh[r8][0]) + dot4(a1,wWh[r8][1])
                    + dot4(a2,wWh[r8][2]) + dot4(a3,wWh[r8][3]);
          const float4 hhv = *((const float4*)(lds_hh + (bloc << 8)) + l);
          float gac[2];
          #pragma unroll
          for (int gi2 = 0; gi2 < 2; ++gi2)
            gac[gi2] = dot4(a0,wHx[gi2][0]) + dot4(a1,wHx[gi2][1])
                     + dot4(a2,wHx[gi2][2]) + dot4(a3,wHx[gi2][3])
                     + dot4(hhv, wHh[gi2]);
          // ---- GH split-reduce: 8 vals over 64 lanes ----
          {
            const bool b5 = (l & 32), b4 = (l & 16), b3 = (l & 8);
            #pragma unroll
            for (int q = 0; q < 4; ++q){
              float snd = b5 ? acc[q] : acc[q+4];
              float rcv = __shfl_xor(snd, 32, 64);
              acc[q] = (b5 ? acc[q+4] : acc[q]) + rcv;
            }
            #pragma unroll
            for (int q = 0; q < 2; ++q){
              float snd = b4 ? acc[q] : acc[q+2];
              float rcv = __shfl_xor(snd, 16, 64);
              acc[q] = (b4 ? acc[q+2] : acc[q]) + rcv;
            }
            {
              float snd = b3 ? acc[0] : acc[1];
              float rcv = __shfl_xor(snd, 8, 64);
              acc[0] = (b3 ? acc[1] : acc[0]) + rcv;
            }
            acc[0] += __shfl_xor(acc[0], 4, 64);
            acc[0] += __shfl_xor(acc[0], 2, 64);
            acc[0] += __shfl_xor(acc[0], 1, 64);
            if ((l & 7) == 0){
              int v = ((l>>5)&1)*4 + ((l>>4)&1)*2 + ((l>>3)&1);
              lds_GH[(b << 4) + (2*rh + (v>>2))*4 + (v&3)] = acc[0];
            }
          }
          // ---- G split-reduce: 2 vals over 64 lanes ----
          {
            float snd = (l & 32) ? gac[0] : gac[1];
            float rcv = __shfl_xor(snd, 32, 64);
            float s = ((l & 32) ? gac[1] : gac[0]) + rcv;
            s += __shfl_xor(s, 16, 64);
            s += __shfl_xor(s, 8, 64);
            s += __shfl_xor(s, 4, 64);
            s += __shfl_xor(s, 2, 64);
            s += __shfl_xor(s, 1, 64);
            if ((l & 31) == 0) lds_Gp[(b << 2) + 2*rh + (l >> 5)] = s;
          }
          // ---- proj row ----
          if (isproj){
            float ya = dot4(a0,wPj[0]) + dot4(a1,wPj[1]) + dot4(a2,wPj[2]) + dot4(a3,wPj[3]);
            ya += __shfl_xor(ya, 32, 64);
            ya += __shfl_xor(ya, 16, 64);
            ya += __shfl_xor(ya, 8, 64);
            ya += __shfl_xor(ya, 4, 64);
            ya += __shfl_xor(ya, 2, 64);
            ya += __shfl_xor(ya, 1, 64);
            if (l == 0) yws[(b << 7) + prow] = ya + pjb;
          }
        }
      }
    } else {
      // epilogue: proj only, h from global
      if (isproj){
        for (int b = 0; b < 128; ++b){
          const float4* h4 = (const float4*)(hws + (b << 10)) + l*4;
          float ya = dot4(h4[0],wPj[0]) + dot4(h4[1],wPj[1]) + dot4(h4[2],wPj[2]) + dot4(h4[3],wPj[3]);
          ya += __shfl_xor(ya, 32, 64);
          ya += __shfl_xor(ya, 16, 64);
          ya += __shfl_xor(ya, 8, 64);
          ya += __shfl_xor(ya, 4, 64);
          ya += __shfl_xor(ya, 2, 64);
          ya += __shfl_xor(ya, 1, 64);
          if (l == 0) yws[(b << 7) + prow] = ya + pjb;
        }
      }
    }
    grid.sync();

    //---------------- P2: sampling (redundant per block) + hyper ----------------
    if (tid < 128){
      const int b = tid;
      if (t >= 1){
        const float* yb = yws + (b << 7);
        int km = 0; float best = -1e30f;
        for (int m = 0; m < 20; ++m){
          float v = yb[m] + gumb(umix[((t-1)*128 + b)*20 + m]);
          if (v > best){ best = v; km = m; }
        }
        const float mx = yb[20+km], my = yb[40+km];
        const float sx = expf(yb[60+km]), sy = expf(yb[80+km]);
        const float rho = tanhf(yb[100+km]);
        const float e0 = eps_[((t-1)*128 + b)*2 + 0], e1 = eps_[((t-1)*128 + b)*2 + 1];
        const float dxs = mx + sx*e0;
        const float dys = my + sy*(rho*e0 + sqrtf(1.0f - rho*rho)*e1);
        int pp = 0; best = -1e30f;
        for (int p = 0; p < 3; ++p){
          float v = yb[120+p] + gumb(upen[((t-1)*128 + b)*3 + p]);
          if (v > best){ best = v; pp = p; }
        }
        float s0,s1,s2,s3,s4;
        if (pp == 2){ s0=0.f; s1=0.f; s2=0.f; s3=0.f; s4=1.f; }
        else { s0=dxs; s1=dys; s2=(pp==0)?1.f:0.f; s3=(pp==1)?1.f:0.f; s4=0.f; }
        if (bid == 0){
          float* o = out + ((t-1)*128 + b)*5;
          o[0]=s0; o[1]=s1; o[2]=s2; o[3]=s3; o[4]=s4;
        }
        lds_prev[b*8+0]=s0; lds_prev[b*8+1]=s1; lds_prev[b*8+2]=s2;
        lds_prev[b*8+3]=s3; lds_prev[b*8+4]=s4;
      }
      if (full){
        const float pv0 = lds_prev[b*8+0], pv1 = lds_prev[b*8+1], pv2 = lds_prev[b*8+2],
                    pv3 = lds_prev[b*8+3], pv4 = lds_prev[b*8+4];
        float gv[4];
        #pragma unroll
        for (int gi = 0; gi < 4; ++gi)
          gv[gi] = lds_Gp[(b << 2) + gi] + cg4r[gi]
                 + pv0*lds_hwxp[gi*5+0] + pv1*lds_hwxp[gi*5+1] + pv2*lds_hwxp[gi*5+2]
                 + pv3*lds_hwxp[gi*5+3] + pv4*lds_hwxp[gi*5+4];
        const float chn = sigf(gv[1])*chst + sigf(gv[0])*tanhf(gv[2]);
        chst = chn;
        const float hhn = sigf(gv[3])*tanhf(chn);
        hhws[(b << 8) + bid] = hhn;
      }
    }
    if (!full) break;
    grid.sync();

    //---------------- P3: dX/dH/dB via Weff + main LSTM ----------------
    {
      const int g3 = l & 31, kh = l >> 5;
      const int kq = ((w & 1) << 1) + kh;
      const int bq3 = w >> 1;
      float4 wf[12][2];
      #pragma unroll
      for (int m = 0; m < 3; ++m)
        #pragma unroll
        for (int j = 0; j < 4; ++j){
          const float4* p = (const float4*)(weffw + (size_t)bid*12288 + m*4096 + ((kq*4+j) << 8) + g3*8);
          wf[m*4+j][0] = p[0]; wf[m*4+j][1] = p[1];
        }
      float* lds_scr = lds_h;   // alias (safe: P1 done, next P1 after grid.sync)
      const float4* hp = (const float4*)(hhws + ((bq3*32) << 8)) + g3*2;
      float4 c0 = hp[0], c1 = hp[1];
      for (int it = 0; it < 32; ++it){
        float4 n0, n1;
        if (it < 31){ n0 = hp[(it+1)*64]; n1 = hp[(it+1)*64 + 1]; }
        const int b = bq3*32 + it;
        float v[12];
        #pragma unroll
        for (int q = 0; q < 12; ++q) v[q] = dot4(c0, wf[q][0]) + dot4(c1, wf[q][1]);
        // split-reduce 12 vals over 32 lanes:
        //   mask16 split -> 6 vals, mask8 split -> 3 vals,
        //   then ab = split(v0,v1) over mask4 + butterfly(2,1);
        //   v2 full butterfly over masks 4,2,1.
        {
          const bool b4 = (l & 16), b3 = (l & 8);
          #pragma unroll
          for (int q = 0; q < 6; ++q){
            float snd = b4 ? v[q] : v[q+6];
            float rcv = __shfl_xor(snd, 16, 64);
            v[q] = (b4 ? v[q+6] : v[q]) + rcv;
          }
          #pragma unroll
          for (int q = 0; q < 3; ++q){
            float snd = b3 ? v[q] : v[q+3];
            float rcv = __shfl_xor(snd, 8, 64);
            v[q] = (b3 ? v[q+3] : v[q]) + rcv;
          }
          float snd = (l & 4) ? v[0] : v[1];
          float rcv = __shfl_xor(snd, 4, 64);
          float ab = ((l & 4) ? v[1] : v[0]) + rcv;   // v0 on l&4==0, v1 on l&4==1; bit2 done
          ab += __shfl_xor(ab, 2, 64);
          ab += __shfl_xor(ab, 1, 64);
          float c2 = v[2];
          c2 += __shfl_xor(c2, 4, 64);
          c2 += __shfl_xor(c2, 2, 64);
          c2 += __shfl_xor(c2, 1, 64);
          const int base = (b4 ? 6 : 0) + (b3 ? 3 : 0);
          if ((l & 7) == 0){
            lds_scr[b*48 + kq*12 + base + 0] = ab;   // v0
            lds_scr[b*48 + kq*12 + base + 2] = c2;   // v2
          } else if ((l & 7) == 4){
            lds_scr[b*48 + kq*12 + base + 1] = ab;   // v1
          }
        }
        c0 = n0; c1 = n1;
      }
      __syncthreads();
      // elementwise LSTM for (b = eb, j = ej)
      {
        float pv[5];
        #pragma unroll
        for (int p = 0; p < 5; ++p) pv[p] = lds_prev[eb*8 + p];
        float pre[4];
        #pragma unroll
        for (int k = 0; k < 4; ++k){
          const float dXv = lds_scr[eb*48 + k*12 + ej];
          const float dHv = lds_scr[eb*48 + k*12 + 4 + ej];
          const float dBv = lds_scr[eb*48 + k*12 + 8 + ej];
          float gxv = cgxr[k];
          #pragma unroll
          for (int p = 0; p < 5; ++p) gxv += pv[p]*lds_wxp[(k*4+ej)*5 + p];
          pre[k] = dXv*gxv + dHv*lds_GH[(eb << 4) + k*4 + ej] + dBv + lds_b0[k*4+ej];
        }
        const float cn = sigf(pre[1])*cst + sigf(pre[0])*tanhf(pre[2]);
        cst = cn;
        const float hn = sigf(pre[3])*tanhf(cn);
        hws[(eb << 10) + bid*4 + ej] = hn;
      }
    }
    grid.sync();
  }
}

extern "C" void kernel_launch(void* const* d_in, const int* in_sizes, int n_in,
                              void* d_out, int out_size, void* d_ws, size_t ws_size,
                              hipStream_t stream)
{
  const float* z     = (const float*)d_in[0];
  const float* cls   = (const float*)d_in[1];
  const float* fcW   = (const float*)d_in[2];
  const float* fcb   = (const float*)d_in[3];
  const float* Wx    = (const float*)d_in[4];
  const float* Wh    = (const float*)d_in[5];
  const float* bias0 = (const float*)d_in[6];
  const float* hWx   = (const float*)d_in[7];
  const float* hWh   = (const float*)d_in[8];
  const float* hb    = (const float*)d_in[9];
  const float* Whz_x = (const float*)d_in[10];
  const float* Whz_h = (const float*)d_in[11];
  const float* Whz_b = (const float*)d_in[12];
  const float* Wdz_x = (const float*)d_in[13];
  const float* Wdz_h = (const float*)d_in[14];
  const float* Wdz_b = (const float*)d_in[15];
  const float* projW = (const float*)d_in[16];
  const float* projb = (const float*)d_in[17];
  const float* eps_  = (const float*)d_in[18];
  const float* umix  = (const float*)d_in[19];
  const float* upen  = (const float*)d_in[20];
  float* out = (float*)d_out;
  float* ws  = (float*)d_ws;

  void* args[] = { (void*)&z, (void*)&cls, (void*)&fcW, (void*)&fcb, (void*)&Wx, (void*)&Wh,
                   (void*)&bias0, (void*)&hWx, (void*)&hWh, (void*)&hb,
                   (void*)&Whz_x, (void*)&Whz_h, (void*)&Whz_b,
                   (void*)&Wdz_x, (void*)&Wdz_h, (void*)&Wdz_b,
                   (void*)&projW, (void*)&projb, (void*)&eps_, (void*)&umix, (void*)&upen,
                   (void*)&out, (void*)&ws };
  hipLaunchCooperativeKernel((const void*)vae_kernel, dim3(NBLK), dim3(NTHR), args, 0, stream);
}

// Round 6
// 20663.272 us; speedup vs baseline: 3.0746x; 1.1187x over previous
//
#include <hip/hip_runtime.h>
#include <hip/hip_cooperative_groups.h>

namespace cg = cooperative_groups;

#define NBLK 256
#define NTHR 512

// workspace layout (float offsets)
constexpr int WS_H    = 0;            // 128*1024   h state (MALL-coherent via sc stores)
constexpr int WS_HHS  = 131072;       // 128*256    hh state
constexpr int WS_Y    = 163840;       // 128*128    y = proj output
constexpr int WS_WEFF = 180224;       // 256*12288  folded hyper weights (plain, L2-cached)
constexpr int WS_BAR  = WS_WEFF + 256*12288;   // barrier counters (uint): root@0, leaf g @ 32+g*32

__device__ __forceinline__ float dot4(float4 a, float4 b){
  return a.x*b.x + a.y*b.y + a.z*b.z + a.w*b.w;
}
__device__ __forceinline__ float sigf(float x){ return 1.0f/(1.0f + expf(-x)); }
__device__ __forceinline__ float gumb(float u){
  u = fminf(fmaxf(u, 1e-7f), 1.0f - 1e-7f);
  return -logf(-logf(u));
}

// coherent write-through store (reaches MALL; vmcnt-tracked)
__device__ __forceinline__ void st_cg(float* p, float v){
  asm volatile("global_store_dword %0, %1, off sc0 sc1" :: "v"(p), "v"(v) : "memory");
}

// hierarchical flush-free grid barrier.
// release: sc-stores + vmcnt drain. acquire: agent acquire fence (buffer_inv).
__device__ __forceinline__ void gridbar(unsigned* barc, unsigned n){
  asm volatile("s_waitcnt vmcnt(0)" ::: "memory");
  __syncthreads();
  if (threadIdx.x == 0){
    const unsigned g = blockIdx.x >> 5;
    unsigned old = __hip_atomic_fetch_add(barc + 32 + g*32, 1u,
                     __ATOMIC_RELAXED, __HIP_MEMORY_SCOPE_AGENT);
    if (old + 1 == n*32)
      __hip_atomic_fetch_add(barc, 1u, __ATOMIC_RELAXED, __HIP_MEMORY_SCOPE_AGENT);
    while (__hip_atomic_load(barc, __ATOMIC_RELAXED, __HIP_MEMORY_SCOPE_AGENT) < n*8)
      __builtin_amdgcn_s_sleep(1);
  }
  __syncthreads();
  __builtin_amdgcn_fence(__ATOMIC_ACQUIRE, "agent");
}

extern "C" __global__ void __launch_bounds__(NTHR, 2)
vae_kernel(const float* __restrict__ z,     const float* __restrict__ cls,
           const float* __restrict__ fcW,   const float* __restrict__ fcb,
           const float* __restrict__ Wx,    const float* __restrict__ Wh,
           const float* __restrict__ bias0, const float* __restrict__ hWx,
           const float* __restrict__ hWh,   const float* __restrict__ hb,
           const float* __restrict__ Whz_x, const float* __restrict__ Whz_h,
           const float* __restrict__ Whz_b, const float* __restrict__ Wdz_x,
           const float* __restrict__ Wdz_h, const float* __restrict__ Wdz_b,
           const float* __restrict__ projW, const float* __restrict__ projb,
           const float* __restrict__ eps_,  const float* __restrict__ umix,
           const float* __restrict__ upen,
           float* __restrict__ out, float* __restrict__ ws)
{
  cg::grid_group grid = cg::this_grid();
  const int tid = threadIdx.x;
  const int bid = blockIdx.x;
  const int l = tid & 63;          // lane
  const int w = tid >> 6;          // wave 0..7
  const int rq = w & 3;            // gate index (P1/P3)
  const int bh = w >> 2;           // half index (P1: bloc-half, P3: batch-half)

  float* hws   = ws + WS_H;
  float* hhws  = ws + WS_HHS;
  float* yws   = ws + WS_Y;
  float* weffw = ws + WS_WEFF;
  unsigned* barc = (unsigned*)(ws + WS_BAR);

  __shared__ __align__(16) float lds_h[8448];    // P1 h-tile(8192) / P2 y(64x132) / P3 scr48(6144)
  __shared__ __align__(16) float lds_hh[2048];
  __shared__ __align__(16) float lds_GH[2048];   // GH[b][16]
  __shared__ __align__(16) float lds_Gp[512];    // Gp[b][4]
  __shared__ __align__(16) float lds_prev[1024]; // prev[b][8]
  __shared__ float lds_wxp[80];
  __shared__ float lds_hwxp[20];
  __shared__ float lds_b0[16];

  //==================== INIT ====================
  if (bid == 0 && tid < 9){
    unsigned* p = (tid == 0) ? barc : (barc + 32 + (tid-1)*32);
    __hip_atomic_store(p, 0u, __ATOMIC_RELAXED, __HIP_MEMORY_SCOPE_AGENT);
  }

  // --- persistent register weights: wave rq owns gate rq ---
  float4 wWh[4][4];      // Wh rows rq*1024 + bid*4 + j ; lane k-slice m*256 + l*4
  #pragma unroll
  for (int j = 0; j < 4; ++j){
    const int row = rq*1024 + bid*4 + j;
    #pragma unroll
    for (int m = 0; m < 4; ++m)
      wWh[j][m] = *((const float4*)(Wh + ((size_t)row << 10) + m*256) + l);
  }
  float4 wHx[4];         // hWx row rq*256+bid, h-cols 143 + m*256 + l*4
  {
    const int row = rq*256 + bid;
    #pragma unroll
    for (int m = 0; m < 4; ++m){
      const float* s = hWx + (size_t)row*1167 + 143 + m*256 + l*4;
      wHx[m] = make_float4(s[0], s[1], s[2], s[3]);
    }
  }
  float4 wHh = *((const float4*)(hWh + ((size_t)(rq*256 + bid) << 8)) + l);

  const bool isproj = (bid >= 128 && bid < 251);
  const int prow = bid - 128;
  float4 wPj[4] = {make_float4(0,0,0,0),make_float4(0,0,0,0),make_float4(0,0,0,0),make_float4(0,0,0,0)};
  float pjb = 0.f;
  if (isproj){
    #pragma unroll
    for (int m = 0; m < 4; ++m)
      wPj[m] = *((const float4*)(projW + ((size_t)prow << 10) + m*256) + l);
    pjb = projb[prow];
  }

  // --- per-thread elementwise state (b = tid>>2, j = tid&3) ---
  const int eb = tid >> 2, ej = tid & 3;
  float cgxr[4];
  #pragma unroll
  for (int k = 0; k < 4; ++k){
    const float* wr = Wx + (size_t)(k*1024 + bid*4 + ej)*143;
    float a = 0.f;
    for (int n = 0; n < 10; ++n) a += cls[eb*10+n]*wr[5+n];
    const float* zr = z + (eb << 7);
    #pragma unroll 8
    for (int i = 0; i < 128; ++i) a += zr[i]*wr[15+i];
    cgxr[k] = a;
  }
  float cst;
  {
    int col = 1024 + bid*4 + ej;
    float a = fcb[col];
    const float* wr = fcW + (col << 7);
    const float* zr = z + (eb << 7);
    #pragma unroll 8
    for (int i = 0; i < 128; ++i) a += zr[i]*wr[i];
    cst = tanhf(a);
  }
  {
    int col = bid*4 + ej;
    float a = fcb[col];
    const float* wr = fcW + (col << 7);
    const float* zr = z + (eb << 7);
    #pragma unroll 8
    for (int i = 0; i < 128; ++i) a += zr[i]*wr[i];
    st_cg(&hws[(eb << 10) + col], tanhf(a));
  }
  float cg4r[4] = {0,0,0,0};
  float chst = 0.f;
  if (tid < 128){
    int b = tid;
    const float* zr = z + (b << 7);
    #pragma unroll
    for (int gi = 0; gi < 4; ++gi){
      int row = gi*256 + bid;
      const float* wr = hWx + (size_t)row*1167;
      float a = hb[row];
      for (int n = 0; n < 10; ++n) a += cls[b*10+n]*wr[5+n];
      #pragma unroll 8
      for (int i = 0; i < 128; ++i) a += zr[i]*wr[15+i];
      cg4r[gi] = a;
    }
    {
      int col = 2304 + bid;
      float a = fcb[col];
      const float* wr = fcW + (col << 7);
      #pragma unroll 8
      for (int i = 0; i < 128; ++i) a += zr[i]*wr[i];
      chst = tanhf(a);
    }
    {
      int col = 2048 + bid;
      float a = fcb[col];
      const float* wr = fcW + (col << 7);
      #pragma unroll 8
      for (int i = 0; i < 128; ++i) a += zr[i]*wr[i];
      st_cg(&hhws[(b << 8) + bid], tanhf(a));
    }
    lds_prev[tid*8+0] = 0.f; lds_prev[tid*8+1] = 0.f; lds_prev[tid*8+2] = 1.f;
    lds_prev[tid*8+3] = 0.f; lds_prev[tid*8+4] = 0.f;
  }
  if (tid < 80){
    int r16 = tid/5, p = tid - r16*5;
    lds_wxp[tid] = Wx[(size_t)((r16>>2)*1024 + bid*4 + (r16&3))*143 + p];
  }
  if (tid < 20){
    int gi = tid/5, p = tid - gi*5;
    lds_hwxp[tid] = hWx[(size_t)(gi*256 + bid)*1167 + p];
  }
  if (tid < 16) lds_b0[tid] = bias0[(tid>>2)*1024 + bid*4 + (tid&3)];

  // --- Weff fold: Weff_m[r=k*4+j][c] = sum_z Wdz_m[k*1024+bid*4+j][z] * Whz_m[k*64+z][c] ---
  {
    const float* Wdzp[3] = {Wdz_x, Wdz_h, Wdz_b};
    const float* Whzp[3] = {Whz_x, Whz_h, Whz_b};
    for (int n = 0; n < 24; ++n){
      int gidx = tid + 512*n;
      int m = gidx >> 12, rem = gidx & 4095;
      int r = rem >> 8, c = rem & 255;
      int k = r >> 2, j = r & 3;
      const float* wd = Wdzp[m] + (size_t)(k*1024 + bid*4 + j)*64;
      const float* wzb = Whzp[m] + c;
      float a = 0.f;
      #pragma unroll 8
      for (int zz = 0; zz < 64; ++zz) a += wd[zz]*wzb[(k*64+zz) << 8];
      weffw[(size_t)bid*12288 + gidx] = a;
    }
  }
  grid.sync();   // heavyweight once: publishes init state (incl. weffw wbl2) + zeroed counters

  unsigned barno = 0;

  //==================== time loop ====================
  for (int t = 0; t <= 128; ++t){
    //---------------- P1: GH, Gp, y from h_t ----------------
    {
      const float4* hsrc  = (const float4*)hws;
      const float4* hhsrc = (const float4*)hhws;
      float4 s0 = hsrc[tid], s1 = hsrc[512+tid], s2 = hsrc[1024+tid], s3 = hsrc[1536+tid];
      float4 sh = hhsrc[tid];
      for (int tile = 0; tile < 16; ++tile){
        __syncthreads();
        {
          float4* hd = (float4*)lds_h;
          hd[tid] = s0; hd[512+tid] = s1; hd[1024+tid] = s2; hd[1536+tid] = s3;
          ((float4*)lds_hh)[tid] = sh;
        }
        __syncthreads();
        if (tile < 15){
          const int o = (tile+1)*2048;
          s0 = hsrc[o+tid]; s1 = hsrc[o+512+tid]; s2 = hsrc[o+1024+tid]; s3 = hsrc[o+1536+tid];
          sh = hhsrc[(tile+1)*512 + tid];
        }
        #pragma unroll
        for (int u = 0; u < 4; ++u){
          const int bloc = bh*4 + u;
          const int b = tile*8 + bloc;
          const float4* h4 = (const float4*)(lds_h + (bloc << 10));
          const float4 a0 = h4[l], a1 = h4[64+l], a2 = h4[128+l], a3 = h4[192+l];
          float acc[4];
          #pragma unroll
          for (int j = 0; j < 4; ++j)
            acc[j] = dot4(a0,wWh[j][0]) + dot4(a1,wWh[j][1])
                   + dot4(a2,wWh[j][2]) + dot4(a3,wWh[j][3]);
          const float4 hhv = ((const float4*)lds_hh)[(bloc << 6) + l];
          float gac = dot4(a0,wHx[0]) + dot4(a1,wHx[1]) + dot4(a2,wHx[2]) + dot4(a3,wHx[3])
                    + dot4(hhv, wHh);
          // GH split-reduce: 4 vals over 64 lanes
          {
            const bool b5 = (l & 32), b4 = (l & 16);
            #pragma unroll
            for (int q = 0; q < 2; ++q){
              float snd = b5 ? acc[q] : acc[q+2];
              float rcv = __shfl_xor(snd, 32, 64);
              acc[q] = (b5 ? acc[q+2] : acc[q]) + rcv;
            }
            float snd = b4 ? acc[0] : acc[1];
            float rcv = __shfl_xor(snd, 16, 64);
            float s = (b4 ? acc[1] : acc[0]) + rcv;
            s += __shfl_xor(s, 8, 64);
            s += __shfl_xor(s, 4, 64);
            s += __shfl_xor(s, 2, 64);
            s += __shfl_xor(s, 1, 64);
            if ((l & 15) == 0)
              lds_GH[(b << 4) + rq*4 + (b5 ? 2 : 0) + (b4 ? 1 : 0)] = s;
          }
          // Gp reduce: full butterfly
          {
            float s = gac;
            s += __shfl_xor(s, 32, 64);
            s += __shfl_xor(s, 16, 64);
            s += __shfl_xor(s, 8, 64);
            s += __shfl_xor(s, 4, 64);
            s += __shfl_xor(s, 2, 64);
            s += __shfl_xor(s, 1, 64);
            if (l == 0) lds_Gp[(b << 2) + rq] = s;
          }
          // proj row (only gate-0 waves; covers all 8 blocs)
          if (isproj && rq == 0){
            float ya = dot4(a0,wPj[0]) + dot4(a1,wPj[1]) + dot4(a2,wPj[2]) + dot4(a3,wPj[3]);
            ya += __shfl_xor(ya, 32, 64);
            ya += __shfl_xor(ya, 16, 64);
            ya += __shfl_xor(ya, 8, 64);
            ya += __shfl_xor(ya, 4, 64);
            ya += __shfl_xor(ya, 2, 64);
            ya += __shfl_xor(ya, 1, 64);
            if (l == 0) st_cg(&yws[(b << 7) + prow], ya + pjb);
          }
        }
      }
    }
    gridbar(barc, ++barno);

    //---------------- P2: sampling (t-1, redundant per block) + hyper ----------------
    if (t >= 1){
      for (int c = 0; c < 2; ++c){
        const float4* ysrc = (const float4*)(yws + c*8192);
        float4 q0 = ysrc[tid*4], q1 = ysrc[tid*4+1], q2 = ysrc[tid*4+2], q3 = ysrc[tid*4+3];
        __syncthreads();
        {
          float4* dst = (float4*)(lds_h + (tid>>3)*132 + (tid&7)*16);
          dst[0]=q0; dst[1]=q1; dst[2]=q2; dst[3]=q3;
        }
        __syncthreads();
        if (tid < 64){
          const int b = c*64 + tid;
          const float* yb = lds_h + tid*132;
          int km = 0; float best = -1e30f;
          for (int m = 0; m < 20; ++m){
            float v = yb[m] + gumb(umix[((t-1)*128 + b)*20 + m]);
            if (v > best){ best = v; km = m; }
          }
          const float mx = yb[20+km], my = yb[40+km];
          const float sx = expf(yb[60+km]), sy = expf(yb[80+km]);
          const float rho = tanhf(yb[100+km]);
          const float e0 = eps_[((t-1)*128 + b)*2 + 0], e1 = eps_[((t-1)*128 + b)*2 + 1];
          const float dxs = mx + sx*e0;
          const float dys = my + sy*(rho*e0 + sqrtf(1.0f - rho*rho)*e1);
          int pp = 0; best = -1e30f;
          for (int p = 0; p < 3; ++p){
            float v = yb[120+p] + gumb(upen[((t-1)*128 + b)*3 + p]);
            if (v > best){ best = v; pp = p; }
          }
          float s0,s1,s2,s3,s4;
          if (pp == 2){ s0=0.f; s1=0.f; s2=0.f; s3=0.f; s4=1.f; }
          else { s0=dxs; s1=dys; s2=(pp==0)?1.f:0.f; s3=(pp==1)?1.f:0.f; s4=0.f; }
          if (bid == 0){
            float* o = out + ((t-1)*128 + b)*5;
            st_cg(o+0, s0); st_cg(o+1, s1); st_cg(o+2, s2); st_cg(o+3, s3); st_cg(o+4, s4);
          }
          lds_prev[b*8+0]=s0; lds_prev[b*8+1]=s1; lds_prev[b*8+2]=s2;
          lds_prev[b*8+3]=s3; lds_prev[b*8+4]=s4;
        }
      }
      __syncthreads();
    }
    if (t == 128) break;
    if (tid < 128){
      const int b = tid;
      const float pv0 = lds_prev[b*8+0], pv1 = lds_prev[b*8+1], pv2 = lds_prev[b*8+2],
                  pv3 = lds_prev[b*8+3], pv4 = lds_prev[b*8+4];
      float gv[4];
      #pragma unroll
      for (int gi = 0; gi < 4; ++gi)
        gv[gi] = lds_Gp[(b << 2) + gi] + cg4r[gi]
               + pv0*lds_hwxp[gi*5+0] + pv1*lds_hwxp[gi*5+1] + pv2*lds_hwxp[gi*5+2]
               + pv3*lds_hwxp[gi*5+3] + pv4*lds_hwxp[gi*5+4];
      const float chn = sigf(gv[1])*chst + sigf(gv[0])*tanhf(gv[2]);
      chst = chn;
      const float hhn = sigf(gv[3])*tanhf(chn);
      st_cg(&hhws[(b << 8) + bid], hhn);
    }
    gridbar(barc, ++barno);

    //---------------- P3: dX/dH/dB via Weff + main LSTM ----------------
    {
      // wave: gate g = rq, batches bh*64 .. +63 ; lane K-slice l*4..+3 of 256
      float4 wf[12];
      #pragma unroll
      for (int m = 0; m < 3; ++m)
        #pragma unroll
        for (int j = 0; j < 4; ++j)
          wf[m*4+j] = *((const float4*)(weffw + (size_t)bid*12288 + m*4096 + ((rq*4+j) << 8)) + l);
      float* lds_scr = lds_h;
      const float4* hq = (const float4*)hhws;   // quad index b*64 + l
      const int b0 = bh*64;
      float4 pf[4];
      #pragma unroll
      for (int i = 0; i < 4; ++i) pf[i] = hq[(b0 + i)*64 + l];
      #pragma unroll 4
      for (int it = 0; it < 64; ++it){
        const float4 ch = pf[it & 3];
        if (it < 60) pf[it & 3] = hq[(b0 + it + 4)*64 + l];
        const int b = b0 + it;
        float v[12];
        #pragma unroll
        for (int q = 0; q < 12; ++q) v[q] = dot4(ch, wf[q]);
        // split-reduce 12 vals over 64 lanes: mask32 (12->6), mask16 (6->3),
        // then ab=split(v0,v1,mask8)+bfly(4,2,1); v2 full bfly(8,4,2,1)
        {
          const bool b5 = (l & 32), b4 = (l & 16), b3 = (l & 8);
          #pragma unroll
          for (int q = 0; q < 6; ++q){
            float snd = b5 ? v[q] : v[q+6];
            float rcv = __shfl_xor(snd, 32, 64);
            v[q] = (b5 ? v[q+6] : v[q]) + rcv;
          }
          #pragma unroll
          for (int q = 0; q < 3; ++q){
            float snd = b4 ? v[q] : v[q+3];
            float rcv = __shfl_xor(snd, 16, 64);
            v[q] = (b4 ? v[q+3] : v[q]) + rcv;
          }
          float snd = b3 ? v[0] : v[1];
          float rcv = __shfl_xor(snd, 8, 64);
          float ab = (b3 ? v[1] : v[0]) + rcv;
          ab += __shfl_xor(ab, 4, 64);
          ab += __shfl_xor(ab, 2, 64);
          ab += __shfl_xor(ab, 1, 64);
          float c2 = v[2];
          c2 += __shfl_xor(c2, 8, 64);
          c2 += __shfl_xor(c2, 4, 64);
          c2 += __shfl_xor(c2, 2, 64);
          c2 += __shfl_xor(c2, 1, 64);
          const int base = (b5 ? 6 : 0) + (b4 ? 3 : 0);
          if ((l & 15) == 0){
            lds_scr[b*48 + rq*12 + base + 0] = ab;
            lds_scr[b*48 + rq*12 + base + 2] = c2;
          } else if ((l & 15) == 8){
            lds_scr[b*48 + rq*12 + base + 1] = ab;
          }
        }
      }
      __syncthreads();
      // elementwise main LSTM (b = eb, col j = ej)
      {
        float pv[5];
        #pragma unroll
        for (int p = 0; p < 5; ++p) pv[p] = lds_prev[eb*8 + p];
        float pre[4];
        #pragma unroll
        for (int k = 0; k < 4; ++k){
          const float dXv = lds_scr[eb*48 + k*12 + ej];
          const float dHv = lds_scr[eb*48 + k*12 + 4 + ej];
          const float dBv = lds_scr[eb*48 + k*12 + 8 + ej];
          float gxv = cgxr[k];
          #pragma unroll
          for (int p = 0; p < 5; ++p) gxv += pv[p]*lds_wxp[(k*4+ej)*5 + p];
          pre[k] = dXv*gxv + dHv*lds_GH[(eb << 4) + k*4 + ej] + dBv + lds_b0[k*4+ej];
        }
        const float cn = sigf(pre[1])*cst + sigf(pre[0])*tanhf(pre[2]);
        cst = cn;
        const float hn = sigf(pre[3])*tanhf(cn);
        st_cg(&hws[(eb << 10) + bid*4 + ej], hn);
      }
    }
    gridbar(barc, ++barno);
  }
}

extern "C" void kernel_launch(void* const* d_in, const int* in_sizes, int n_in,
                              void* d_out, int out_size, void* d_ws, size_t ws_size,
                              hipStream_t stream)
{
  const float* z     = (const float*)d_in[0];
  const float* cls   = (const float*)d_in[1];
  const float* fcW   = (const float*)d_in[2];
  const float* fcb   = (const float*)d_in[3];
  const float* Wx    = (const float*)d_in[4];
  const float* Wh    = (const float*)d_in[5];
  const float* bias0 = (const float*)d_in[6];
  const float* hWx   = (const float*)d_in[7];
  const float* hWh   = (const float*)d_in[8];
  const float* hb    = (const float*)d_in[9];
  const float* Whz_x = (const float*)d_in[10];
  const float* Whz_h = (const float*)d_in[11];
  const float* Whz_b = (const float*)d_in[12];
  const float* Wdz_x = (const float*)d_in[13];
  const float* Wdz_h = (const float*)d_in[14];
  const float* Wdz_b = (const float*)d_in[15];
  const float* projW = (const float*)d_in[16];
  const float* projb = (const float*)d_in[17];
  const float* eps_  = (const float*)d_in[18];
  const float* umix  = (const float*)d_in[19];
  const float* upen  = (const float*)d_in[20];
  float* out = (float*)d_out;
  float* ws  = (float*)d_ws;

  void* args[] = { (void*)&z, (void*)&cls, (void*)&fcW, (void*)&fcb, (void*)&Wx, (void*)&Wh,
                   (void*)&bias0, (void*)&hWx, (void*)&hWh, (void*)&hb,
                   (void*)&Whz_x, (void*)&Whz_h, (void*)&Whz_b,
                   (void*)&Wdz_x, (void*)&Wdz_h, (void*)&Wdz_b,
                   (void*)&projW, (void*)&projb, (void*)&eps_, (void*)&umix, (void*)&upen,
                   (void*)&out, (void*)&ws };
  (void)hipLaunchCooperativeKernel((const void*)vae_kernel, dim3(NBLK), dim3(NTHR), args, 0, stream);
}